// Round 17
// baseline (200.506 us; speedup 1.0000x reference)
//
#include <hip/hip_runtime.h>

#define B 32768
#define D 1024
#define SEL 512
#define E 6
#define K 3
#define SH 32
#define HID 128
#define NKT 16    // K tiles of 64 (K = D = 1024)

typedef __attribute__((ext_vector_type(8))) short bf16x8;
typedef __attribute__((ext_vector_type(4))) float f32x4;

__device__ __forceinline__ unsigned short f2bf(float f) {
  unsigned u = __float_as_uint(f);
  return (unsigned short)((u + 0x7fffu + ((u >> 16) & 1u)) >> 16);
}
__device__ __forceinline__ float bf2f(unsigned short h) {
  return __uint_as_float((unsigned)h << 16);
}

__device__ __forceinline__ void gload_lds16(const void* g, void* l) {
  __builtin_amdgcn_global_load_lds(
      (const __attribute__((address_space(1))) void*)g,
      (__attribute__((address_space(3))) void*)l, 16, 0, 0);
}

// ---------------- K0: per-expert inverse selection map (+ cnt zeroing) -------
__global__ void k_sel(const float* __restrict__ ml, int* __restrict__ inv,
                      int* __restrict__ cnt) {
  __shared__ float row[D];
  const int e = blockIdx.x, t = threadIdx.x;
  if (t == 0) cnt[e] = 0;
  row[t] = ml[e * D + t];
  __syncthreads();
  const float v = row[t];
  int rank = 0;
  for (int i = 0; i < D; ++i) {
    float u = row[i];
    rank += (u > v) || (u == v && i < t);
  }
  inv[e * D + t] = (rank < SEL) ? rank : -1;
}

// ---------------- K1a: WoWsp + bfull + WgS (hi/lo split of Wg, 16-col pad) --
__global__ __launch_bounds__(256) void k_wowsp(
    const float* __restrict__ Wo, const float* __restrict__ Wsp,
    const float* __restrict__ bo, const float* __restrict__ bsp,
    const float* __restrict__ Wg,
    float* __restrict__ WoWsp, float* __restrict__ bfull,
    unsigned short* __restrict__ WgS) {
  __shared__ float red[256];
  const int t = threadIdx.x;
  const int j = t & 31, chunk = t >> 5;
  const int blk = blockIdx.x;
  if (blk < 64) {
    const int i = blk;
    float p = 0.f;
    for (int c = chunk * 64; c < chunk * 64 + 64; ++c)
      p += Wo[i * 512 + c] * Wsp[c * SH + j];
    red[t] = p;
    __syncthreads();
    if (t < 32) {
      float s = 0.f;
      #pragma unroll
      for (int k = 0; k < 8; ++k) s += red[k * 32 + j];
      WoWsp[i * SH + j] = s;
    }
  } else if (blk == 64) {
    float p = 0.f;
    for (int c = chunk * 64; c < chunk * 64 + 64; ++c)
      p += bo[c] * Wsp[c * SH + j];
    red[t] = p;
    __syncthreads();
    if (t < 32) {
      float s = bsp[j];
      #pragma unroll
      for (int k = 0; k < 8; ++k) s += red[k * 32 + j];
      bfull[j] = s;
    }
  } else {
    const int idx = (blk - 65) * 256 + t;   // 0..16383
    const int col = idx >> 10, k = idx & 1023;
    float wv = (col < E) ? Wg[(size_t)k * E + col] : 0.f;
    unsigned short hi = f2bf(wv);
    unsigned short lo = f2bf(wv - bf2f(hi));
    WgS[col * D + k] = hi;
    WgS[16 * D + col * D + k] = lo;
  }
}

// ---------------- K1b: Wfull = Wv @ WoWsp (512x32) ----------------
__global__ __launch_bounds__(256) void k_wfull2(
    const float* __restrict__ Wv, const float* __restrict__ WoWsp,
    float* __restrict__ Wfull) {
  __shared__ float wsh[64 * SH];
  const int t = threadIdx.x;
  for (int idx = t; idx < 64 * SH; idx += 256) wsh[idx] = WoWsp[idx];
  __syncthreads();
  const int c = blockIdx.x * 8 + (t >> 5), j = t & 31;
  float p = 0.f;
  #pragma unroll 8
  for (int i = 0; i < 64; ++i) p += Wv[c * 64 + i] * wsh[i * SH + j];
  Wfull[c * SH + j] = p;
}

// ---------------- K2: W1comb[e][h][d] bf16 (scatter + folded sinfo) ----------
__global__ __launch_bounds__(256) void k_w1c(
    const float* __restrict__ W1, const float* __restrict__ b1,
    const int* __restrict__ inv, const float* __restrict__ Wfull,
    const float* __restrict__ bfull,
    unsigned short* __restrict__ W1eT, float* __restrict__ b1c) {
  __shared__ float w1b[SH];
  __shared__ float bf[SH];
  const int e = blockIdx.x >> 7, h = blockIdx.x & 127;
  const int t = threadIdx.x;
  const float* We = W1 + (size_t)e * (SEL + SH) * HID;
  if (t < SH) { w1b[t] = We[(size_t)(SEL + t) * HID + h]; bf[t] = bfull[t]; }
  __syncthreads();
  const int* iv = inv + e * D;
  unsigned short* dst = W1eT + ((size_t)e * HID + h) * D;
  #pragma unroll
  for (int it = 0; it < 4; ++it) {
    int d = t + it * 256;
    int s = iv[d];
    float v = (s >= 0) ? We[(size_t)s * HID + h] : 0.f;
    if (d >= 512) {
      const float* wf = Wfull + (size_t)(d - 512) * SH;
      float p = 0.f;
      #pragma unroll
      for (int j = 0; j < SH; ++j) p += wf[j] * w1b[j];
      v += p;
    }
    dst[d] = f2bf(v);
  }
  if (t == 0) {
    float p = b1[e * HID + h];
    for (int j = 0; j < SH; ++j) p += bf[j] * w1b[j];
    b1c[e * HID + h] = p;
  }
}

// ---------------- K3: K-split MFMA gate (no xbf; pure read + partials) ------
// grid = (B/64)*4 = 2048 (8 blocks/CU). Block (bm, ks) stages 64 tokens x
// K-quarter, hi/lo MFMA, writes raw partials gpart[tok][ks][8].
__global__ __launch_bounds__(256) void k_xgate(
    const float* __restrict__ x, const unsigned short* __restrict__ WgS,
    float* __restrict__ gpart) {
  __shared__ __align__(16) char ldsAh[64 * 128];   // 8 KB
  __shared__ __align__(16) char ldsAl[64 * 128];   // 8 KB
  __shared__ __align__(16) char ldsW[4096];        // 32 colrows x 128B (hi|lo)
  const int t = threadIdx.x;
  const int bm = blockIdx.x >> 2;      // 64-token tile
  const int ks = blockIdx.x & 3;       // K quarter (4 kt each)
  const int w = t >> 6, lane = t & 63;
  const int g = lane >> 4, j = lane & 15;
  const int tok0 = bm * 64;
  const int swz = ((lane & 7) * 16) ^ ((lane >> 3) << 4);

  const char* srcW = (const char*)WgS +
                     (size_t)(w * 8 + (lane >> 3)) * (D * 2) + swz;

  f32x4 acc = {0.f, 0.f, 0.f, 0.f};

  for (int i = 0; i < 4; ++i) {
    const int kt = ks * 4 + i;
    if (i) __syncthreads();
    gload_lds16(srcW + kt * 128, ldsW + w * 1024);
    #pragma unroll
    for (int it = 0; it < 4; ++it) {
      int r = (t >> 4) + it * 16;
      const float4 v =
          *(const float4*)(x + (size_t)(tok0 + r) * D + kt * 64 + (t & 15) * 4);
      ushort4 hh, ll;
      hh.x = f2bf(v.x); hh.y = f2bf(v.y); hh.z = f2bf(v.z); hh.w = f2bf(v.w);
      ll.x = f2bf(v.x - bf2f(hh.x)); ll.y = f2bf(v.y - bf2f(hh.y));
      ll.z = f2bf(v.z - bf2f(hh.z)); ll.w = f2bf(v.w - bf2f(hh.w));
      const int ao = r * 128 + (((t & 15) * 8) ^ ((r & 7) << 4));
      *(ushort4*)(ldsAh + ao) = hh;
      *(ushort4*)(ldsAl + ao) = ll;
    }
    __syncthreads();
    #pragma unroll
    for (int kk = 0; kk < 2; ++kk) {
      const int kb = kk * 64 + g * 16;
      const int wo = kb ^ ((j & 7) << 4);
      bf16x8 bh = *(const bf16x8*)(ldsW + j * 128 + wo);
      bf16x8 bl = *(const bf16x8*)(ldsW + 2048 + j * 128 + wo);
      const int row = w * 16 + j;
      const int aoff = row * 128 + (kb ^ ((row & 7) << 4));
      bf16x8 ah = *(const bf16x8*)(ldsAh + aoff);
      bf16x8 al = *(const bf16x8*)(ldsAl + aoff);
      acc = __builtin_amdgcn_mfma_f32_16x16x32_bf16(ah, bh, acc, 0, 0, 0);
      acc = __builtin_amdgcn_mfma_f32_16x16x32_bf16(ah, bl, acc, 0, 0, 0);
      acc = __builtin_amdgcn_mfma_f32_16x16x32_bf16(al, bh, acc, 0, 0, 0);
      acc = __builtin_amdgcn_mfma_f32_16x16x32_bf16(al, bl, acc, 0, 0, 0);
    }
  }
  // C layout: col = lane&15, row(within wave's 16 tokens) = g*4 + ri
  if (j < E) {
    #pragma unroll
    for (int ri = 0; ri < 4; ++ri)
      gpart[(size_t)(tok0 + w * 16 + g * 4 + ri) * 32 + ks * 8 + j] = acc[ri];
  }
}

// ---------------- K4: partial-sum + exact guard + top-3 + compaction --------
__global__ __launch_bounds__(256) void k_gtopk(
    const float* __restrict__ gpart, const float* __restrict__ x,
    const float* __restrict__ Wg, const float* __restrict__ bg,
    int* __restrict__ cnt, int* __restrict__ clist, float* __restrict__ wlist) {
  const int tok = blockIdx.x * 256 + threadIdx.x;
  const int l = threadIdx.x & 63;
  const int wtok0 = tok - l;           // wave's first token
  float gv[E];
  #pragma unroll
  for (int e2 = 0; e2 < E; ++e2) {
    float s = bg[e2];
    #pragma unroll
    for (int ks = 0; ks < 4; ++ks) s += gpart[(size_t)tok * 32 + ks * 8 + e2];
    gv[e2] = s;
  }
  // top-4 gap check (membership boundary = rank2 vs rank3, 0-indexed)
  float s4[4];
  {
    bool used[E] = {};
    #pragma unroll
    for (int k = 0; k < 4; ++k) {
      float best = -1e30f; int bi = 0;
      for (int e2 = 0; e2 < E; ++e2)
        if (!used[e2] && gv[e2] > best) { best = gv[e2]; bi = e2; }
      used[bi] = true; s4[k] = best;
    }
  }
  unsigned long long flags = __ballot(s4[2] - s4[3] < 4e-3f);
  while (flags) {
    const int fl = __ffsll((long long)flags) - 1;
    flags &= flags - 1;
    const int tokf = wtok0 + fl;
    float ex[E] = {};
    for (int i = 0; i < 16; ++i) {
      const int d = l + 64 * i;
      float xv = x[(size_t)tokf * D + d];
      const float* wr = Wg + (size_t)d * E;
      #pragma unroll
      for (int e2 = 0; e2 < E; ++e2) ex[e2] += xv * wr[e2];
    }
    #pragma unroll
    for (int e2 = 0; e2 < E; ++e2) {
      float s = ex[e2];
      s += __shfl_xor(s, 1); s += __shfl_xor(s, 2); s += __shfl_xor(s, 4);
      s += __shfl_xor(s, 8); s += __shfl_xor(s, 16); s += __shfl_xor(s, 32);
      ex[e2] = s;
    }
    if (l == fl) {
      #pragma unroll
      for (int e2 = 0; e2 < E; ++e2) gv[e2] = ex[e2] + bg[e2];
    }
  }
  // top-3 + softmax + ballot compaction
  int idx[K]; float sc[K];
  bool used[E] = {};
  #pragma unroll
  for (int k = 0; k < K; ++k) {
    float best = -1e30f; int bi = 0;
    for (int e2 = 0; e2 < E; ++e2)
      if (!used[e2] && gv[e2] > best) { best = gv[e2]; bi = e2; }
    used[bi] = true; sc[k] = best; idx[k] = bi;
  }
  float s1 = __expf(sc[1] - sc[0]), s2 = __expf(sc[2] - sc[0]);
  float inv_s = 1.f / (1.f + s1 + s2);
  float tw[K] = {inv_s, s1 * inv_s, s2 * inv_s};
  const unsigned long long below = (1ULL << l) - 1ULL;
  #pragma unroll
  for (int e2 = 0; e2 < E; ++e2) {
    int myk = -1;
    #pragma unroll
    for (int k = 0; k < K; ++k) if (idx[k] == e2) myk = k;
    unsigned long long m = __ballot(myk >= 0);
    if (m) {
      int tot = __popcll(m);
      int leader = __ffsll((long long)m) - 1;
      int base = 0;
      if (l == leader) base = atomicAdd(&cnt[e2], tot);
      base = __shfl(base, leader);
      if (myk >= 0) {
        int pos = base + __popcll(m & below);
        clist[e2 * B + pos] = (tok << 2) | myk;
        wlist[e2 * B + pos] = tw[myk];
      }
    }
  }
}

// ---------------- K5: compacted per-expert GEMM (fp32 x, inline cvt) --------
__global__ __launch_bounds__(256) void k_gemm(
    const float* __restrict__ x, const unsigned short* __restrict__ W1eT,
    const int* __restrict__ cnt, const int* __restrict__ clist,
    const float* __restrict__ wlist,
    const float* __restrict__ b1c, const float* __restrict__ W2,
    const float* __restrict__ b2, float* __restrict__ eo4) {
  __shared__ __align__(16) char ldsA[128 * 128];
  __shared__ __align__(16) char ldsB[128 * 128];
  __shared__ int tokl[128];
  __shared__ float red[128];

  const int t = threadIdx.x;
  const int e = blockIdx.x >> 8;     // grid = E * 256
  const int bm = blockIdx.x & 255;
  const int n = cnt[e];
  if (bm * 128 >= n) return;
  const int cb = e * B;

  if (t < 128) {
    int gr = bm * 128 + t;
    tokl[t] = clist[cb + (gr < n ? gr : 0)] >> 2;
  }
  __syncthreads();

  const int w = t >> 6, lane = t & 63;
  const int g = lane >> 4, j = lane & 15;
  const int swz = ((lane & 7) * 16) ^ ((lane >> 3) << 4);

  const char* srcB[4];
  #pragma unroll
  for (int q = 0; q < 4; ++q)
    srcB[q] = (const char*)W1eT +
              (size_t)(e * HID + w * 32 + q * 8 + (lane >> 3)) * (D * 2) + swz;

  f32x4 acc[2][8] = {};

  for (int kt = 0; kt < NKT; ++kt) {
    if (kt) __syncthreads();
    #pragma unroll
    for (int q = 0; q < 4; ++q)
      gload_lds16(srcB[q] + kt * 128, ldsB + w * 4096 + q * 1024);
    // A: fp32 x rows (tokl-gathered, L3-warm), inline cvt, swizzled ds_write
    #pragma unroll
    for (int it = 0; it < 8; ++it) {
      int r = (t >> 4) + it * 16;
      const float4 v =
          *(const float4*)(x + (size_t)tokl[r] * D + kt * 64 + (t & 15) * 4);
      ushort4 h4;
      h4.x = f2bf(v.x); h4.y = f2bf(v.y); h4.z = f2bf(v.z); h4.w = f2bf(v.w);
      *(ushort4*)(ldsA + r * 128 + (((t & 15) * 8) ^ ((r & 7) << 4))) = h4;
    }
    __syncthreads();
    #pragma unroll
    for (int kk = 0; kk < 2; ++kk) {
      const int kb = kk * 64 + g * 16;
      bf16x8 aF[2];
      #pragma unroll
      for (int fm = 0; fm < 2; ++fm) {
        int row = w * 32 + fm * 16 + j;
        aF[fm] = *(const bf16x8*)(ldsA + row * 128 + (kb ^ ((row & 7) << 4)));
      }
      #pragma unroll
      for (int fn = 0; fn < 8; ++fn) {
        int col = fn * 16 + j;
        bf16x8 bF = *(const bf16x8*)(ldsB + col * 128 + (kb ^ ((col & 7) << 4)));
        acc[0][fn] = __builtin_amdgcn_mfma_f32_16x16x32_bf16(aF[0], bF, acc[0][fn], 0, 0, 0);
        acc[1][fn] = __builtin_amdgcn_mfma_f32_16x16x32_bf16(aF[1], bF, acc[1][fn], 0, 0, 0);
      }
    }
  }

  float vb1[8], vw2[8];
  #pragma unroll
  for (int fn = 0; fn < 8; ++fn) {
    int col = fn * 16 + j;
    vb1[fn] = b1c[e * HID + col];
    vw2[fn] = W2[e * HID + col];
  }
  #pragma unroll
  for (int fm = 0; fm < 2; ++fm) {
    #pragma unroll
    for (int r = 0; r < 4; ++r) {
      float s = 0.f;
      #pragma unroll
      for (int fn = 0; fn < 8; ++fn)
        s += fmaxf(acc[fm][fn][r] + vb1[fn], 0.f) * vw2[fn];
      s += __shfl_xor(s, 1); s += __shfl_xor(s, 2);
      s += __shfl_xor(s, 4); s += __shfl_xor(s, 8);
      if (j == 0) red[w * 32 + fm * 16 + g * 4 + r] = s;
    }
  }
  __syncthreads();
  if (t < 128) {
    int gr = bm * 128 + t;
    if (gr < n) {
      int en = clist[cb + gr];
      eo4[(size_t)(en >> 2) * 4 + (en & 3)] = wlist[cb + gr] * (red[t] + b2[e]);
    }
  }
}

// ---------------- K6: sum the 3 weighted slots ----------------
__global__ void k_comb2(const float* __restrict__ eo4, float* __restrict__ out) {
  const int tok = blockIdx.x * 256 + threadIdx.x;
  float4 v = *(const float4*)(eo4 + (size_t)tok * 4);
  out[tok] = v.x + v.y + v.z;
}

extern "C" void kernel_launch(void* const* d_in, const int* in_sizes, int n_in,
                              void* d_out, int out_size, void* d_ws, size_t ws_size,
                              hipStream_t stream) {
  const float* x   = (const float*)d_in[0];
  const float* Wv  = (const float*)d_in[3];
  const float* Wo  = (const float*)d_in[4];
  const float* bo  = (const float*)d_in[5];
  const float* Wsp = (const float*)d_in[6];
  const float* bsp = (const float*)d_in[7];
  const float* Wg  = (const float*)d_in[8];
  const float* bg  = (const float*)d_in[9];
  const float* ml  = (const float*)d_in[10];
  const float* W1  = (const float*)d_in[11];
  const float* b1  = (const float*)d_in[12];
  const float* W2  = (const float*)d_in[13];
  const float* b2  = (const float*)d_in[14];
  float* out = (float*)d_out;

  char* ws = (char*)d_ws;
  int*   inv   = (int*)ws;                          // 24 KB
  float* WoWsp = (float*)(ws + 32768);              // 8 KB
  float* Wfull = (float*)(ws + 49152);              // 64 KB
  float* bfull = (float*)(ws + 114688);             // 128 B
  float* b1c   = (float*)(ws + 118784);             // 3 KB
  int*   cnt   = (int*)(ws + 126976);               // 32 B
  unsigned short* WgS = (unsigned short*)(ws + 131072);  // 64 KB -> 196608
  int*   clist = (int*)(ws + 262144);               // 768 KB -> 1048576
  float* wlist = (float*)(ws + 1048576);            // 768 KB -> 1835008
  float* eo4   = (float*)(ws + 1835008);            // 512 KB -> 2359296
  unsigned short* W1eT = (unsigned short*)(ws + 2359296);  // 1.5 MB -> 3932160
  float* gpart = (float*)(ws + 3932160);            // 4 MB -> 8126464

  k_sel<<<E, D, 0, stream>>>(ml, inv, cnt);
  k_wowsp<<<129, 256, 0, stream>>>(Wo, Wsp, bo, bsp, Wg, WoWsp, bfull, WgS);
  k_wfull2<<<64, 256, 0, stream>>>(Wv, WoWsp, Wfull);
  k_w1c<<<E * HID, 256, 0, stream>>>(W1, b1, inv, Wfull, bfull, W1eT, b1c);
  k_xgate<<<(B / 64) * 4, 256, 0, stream>>>(x, WgS, gpart);
  k_gtopk<<<B / 256, 256, 0, stream>>>(gpart, x, Wg, bg, cnt, clist, wlist);
  k_gemm<<<E * 256, 256, 0, stream>>>(x, W1eT, cnt, clist, wlist, b1c, W2, b2, eo4);
  k_comb2<<<B / 256, 256, 0, stream>>>(eo4, out);
}

// Round 18
// 175.605 us; speedup vs baseline: 1.1418x; 1.1418x over previous
//
#include <hip/hip_runtime.h>

#define B 32768
#define D 1024
#define SEL 512
#define E 6
#define K 3
#define SH 32
#define HID 128
#define NKT 16    // K tiles of 64 (K = D = 1024)

typedef __attribute__((ext_vector_type(8))) short bf16x8;
typedef __attribute__((ext_vector_type(4))) float f32x4;

__device__ __forceinline__ unsigned short f2bf(float f) {
  unsigned u = __float_as_uint(f);
  return (unsigned short)((u + 0x7fffu + ((u >> 16) & 1u)) >> 16);
}
__device__ __forceinline__ float bf2f(unsigned short h) {
  return __uint_as_float((unsigned)h << 16);
}

__device__ __forceinline__ void gload_lds16(const void* g, void* l) {
  __builtin_amdgcn_global_load_lds(
      (const __attribute__((address_space(1))) void*)g,
      (__attribute__((address_space(3))) void*)l, 16, 0, 0);
}

// ---------------- K0: per-expert inverse selection map (+ cnt zeroing) -------
__global__ void k_sel(const float* __restrict__ ml, int* __restrict__ inv,
                      int* __restrict__ cnt) {
  __shared__ float row[D];
  const int e = blockIdx.x, t = threadIdx.x;
  if (t == 0) cnt[e] = 0;
  row[t] = ml[e * D + t];
  __syncthreads();
  const float v = row[t];
  int rank = 0;
  for (int i = 0; i < D; ++i) {
    float u = row[i];
    rank += (u > v) || (u == v && i < t);
  }
  inv[e * D + t] = (rank < SEL) ? rank : -1;
}

// ---------------- K1a: WoWsp + bfull + WgS (hi/lo split of Wg, 16-col pad) --
__global__ __launch_bounds__(256) void k_wowsp(
    const float* __restrict__ Wo, const float* __restrict__ Wsp,
    const float* __restrict__ bo, const float* __restrict__ bsp,
    const float* __restrict__ Wg,
    float* __restrict__ WoWsp, float* __restrict__ bfull,
    unsigned short* __restrict__ WgS) {
  __shared__ float red[256];
  const int t = threadIdx.x;
  const int j = t & 31, chunk = t >> 5;
  const int blk = blockIdx.x;
  if (blk < 64) {
    const int i = blk;
    float p = 0.f;
    for (int c = chunk * 64; c < chunk * 64 + 64; ++c)
      p += Wo[i * 512 + c] * Wsp[c * SH + j];
    red[t] = p;
    __syncthreads();
    if (t < 32) {
      float s = 0.f;
      #pragma unroll
      for (int k = 0; k < 8; ++k) s += red[k * 32 + j];
      WoWsp[i * SH + j] = s;
    }
  } else if (blk == 64) {
    float p = 0.f;
    for (int c = chunk * 64; c < chunk * 64 + 64; ++c)
      p += bo[c] * Wsp[c * SH + j];
    red[t] = p;
    __syncthreads();
    if (t < 32) {
      float s = bsp[j];
      #pragma unroll
      for (int k = 0; k < 8; ++k) s += red[k * 32 + j];
      bfull[j] = s;
    }
  } else {
    const int idx = (blk - 65) * 256 + t;   // 0..16383
    const int col = idx >> 10, k = idx & 1023;
    float wv = (col < E) ? Wg[(size_t)k * E + col] : 0.f;
    unsigned short hi = f2bf(wv);
    unsigned short lo = f2bf(wv - bf2f(hi));
    WgS[col * D + k] = hi;
    WgS[16 * D + col * D + k] = lo;
  }
}

// ---------------- K1b: Wfull = Wv @ WoWsp (512x32) ----------------
__global__ __launch_bounds__(256) void k_wfull2(
    const float* __restrict__ Wv, const float* __restrict__ WoWsp,
    float* __restrict__ Wfull) {
  __shared__ float wsh[64 * SH];
  const int t = threadIdx.x;
  for (int idx = t; idx < 64 * SH; idx += 256) wsh[idx] = WoWsp[idx];
  __syncthreads();
  const int c = blockIdx.x * 8 + (t >> 5), j = t & 31;
  float p = 0.f;
  #pragma unroll 8
  for (int i = 0; i < 64; ++i) p += Wv[c * 64 + i] * wsh[i * SH + j];
  Wfull[c * SH + j] = p;
}

// ---------------- K2: W1comb[e][h][d] bf16 (scatter + folded sinfo) ----------
__global__ __launch_bounds__(256) void k_w1c(
    const float* __restrict__ W1, const float* __restrict__ b1,
    const int* __restrict__ inv, const float* __restrict__ Wfull,
    const float* __restrict__ bfull,
    unsigned short* __restrict__ W1eT, float* __restrict__ b1c) {
  __shared__ float w1b[SH];
  __shared__ float bf[SH];
  const int e = blockIdx.x >> 7, h = blockIdx.x & 127;
  const int t = threadIdx.x;
  const float* We = W1 + (size_t)e * (SEL + SH) * HID;
  if (t < SH) { w1b[t] = We[(size_t)(SEL + t) * HID + h]; bf[t] = bfull[t]; }
  __syncthreads();
  const int* iv = inv + e * D;
  unsigned short* dst = W1eT + ((size_t)e * HID + h) * D;
  #pragma unroll
  for (int it = 0; it < 4; ++it) {
    int d = t + it * 256;
    int s = iv[d];
    float v = (s >= 0) ? We[(size_t)s * HID + h] : 0.f;
    if (d >= 512) {
      const float* wf = Wfull + (size_t)(d - 512) * SH;
      float p = 0.f;
      #pragma unroll
      for (int j = 0; j < SH; ++j) p += wf[j] * w1b[j];
      v += p;
    }
    dst[d] = f2bf(v);
  }
  if (t == 0) {
    float p = b1[e * HID + h];
    for (int j = 0; j < SH; ++j) p += bf[j] * w1b[j];
    b1c[e * HID + h] = p;
  }
}

// ---------------- K3: fused x->bf16 + hi/lo MFMA gate + exact-guard topk ----
// R12 structure + T14 async-STAGE: kt+1's x loads (regs) and W gload_lds
// (double-buffered ldsW) issue before the MFMA phase; they drain at the next
// iteration's first barrier, exactly where consumed.
template<bool WRITE_XBF>
__global__ __launch_bounds__(256) void k_xgate(
    const float* __restrict__ x, const unsigned short* __restrict__ WgS,
    const float* __restrict__ Wg, const float* __restrict__ bg,
    unsigned short* __restrict__ xbf,
    int* __restrict__ cnt, int* __restrict__ clist, float* __restrict__ wlist) {
  __shared__ __align__(16) char ldsAh[64 * 128];   // 8 KB
  __shared__ __align__(16) char ldsAl[64 * 128];   // 8 KB
  __shared__ __align__(16) char ldsW[2][4096];     // double-buffered W (hi|lo)
  __shared__ float gl_s[64][8];
  const int t = threadIdx.x;
  const int bm = blockIdx.x;
  const int w = t >> 6, lane = t & 63;
  const int g = lane >> 4, j = lane & 15;
  const int tok0 = bm * 64;
  const int swz = ((lane & 7) * 16) ^ ((lane >> 3) << 4);
  const int r0 = t >> 4, c16 = t & 15;

  const char* srcW = (const char*)WgS +
                     (size_t)(w * 8 + (lane >> 3)) * (D * 2) + swz;

  f32x4 acc = {0.f, 0.f, 0.f, 0.f};

  // prologue: kt=0 W into ldsW[0]; kt=0 x into registers
  gload_lds16(srcW, ldsW[0] + w * 1024);
  float4 vb0, vb1, vb2, vb3;
  {
    const float* xp = x + (size_t)(tok0 + r0) * D + c16 * 4;
    vb0 = *(const float4*)(xp);
    vb1 = *(const float4*)(xp + 16 * D);
    vb2 = *(const float4*)(xp + 32 * D);
    vb3 = *(const float4*)(xp + 48 * D);
  }

  for (int kt = 0; kt < NKT; ++kt) {
    if (kt) __syncthreads();   // prev MFMA reads done; prefetched W/x complete
    // stage current kt from registers
    {
      float4 vv[4] = {vb0, vb1, vb2, vb3};
      #pragma unroll
      for (int it = 0; it < 4; ++it) {
        const int r = r0 + it * 16;
        float4 v = vv[it];
        ushort4 hh, ll;
        hh.x = f2bf(v.x); hh.y = f2bf(v.y); hh.z = f2bf(v.z); hh.w = f2bf(v.w);
        ll.x = f2bf(v.x - bf2f(hh.x)); ll.y = f2bf(v.y - bf2f(hh.y));
        ll.z = f2bf(v.z - bf2f(hh.z)); ll.w = f2bf(v.w - bf2f(hh.w));
        if (WRITE_XBF)
          *(ushort4*)(xbf + (size_t)(tok0 + r) * D + kt * 64 + c16 * 4) = hh;
        const int ao = r * 128 + ((c16 * 8) ^ ((r & 7) << 4));
        *(ushort4*)(ldsAh + ao) = hh;
        *(ushort4*)(ldsAl + ao) = ll;
      }
    }
    __syncthreads();
    // prefetch kt+1 (in flight across the MFMA phase)
    if (kt + 1 < NKT) {
      gload_lds16(srcW + (kt + 1) * 128, ldsW[(kt + 1) & 1] + w * 1024);
      const float* xp = x + (size_t)(tok0 + r0) * D + (kt + 1) * 64 + c16 * 4;
      vb0 = *(const float4*)(xp);
      vb1 = *(const float4*)(xp + 16 * D);
      vb2 = *(const float4*)(xp + 32 * D);
      vb3 = *(const float4*)(xp + 48 * D);
    }
    // MFMA on current buffers
    const char* Wcur = ldsW[kt & 1];
    #pragma unroll
    for (int kk = 0; kk < 2; ++kk) {
      const int kb = kk * 64 + g * 16;
      const int wo = kb ^ ((j & 7) << 4);
      bf16x8 bh = *(const bf16x8*)(Wcur + j * 128 + wo);
      bf16x8 bl = *(const bf16x8*)(Wcur + 2048 + j * 128 + wo);
      const int row = w * 16 + j;
      const int aoff = row * 128 + (kb ^ ((row & 7) << 4));
      bf16x8 ah = *(const bf16x8*)(ldsAh + aoff);
      bf16x8 al = *(const bf16x8*)(ldsAl + aoff);
      acc = __builtin_amdgcn_mfma_f32_16x16x32_bf16(ah, bh, acc, 0, 0, 0);
      acc = __builtin_amdgcn_mfma_f32_16x16x32_bf16(ah, bl, acc, 0, 0, 0);
      acc = __builtin_amdgcn_mfma_f32_16x16x32_bf16(al, bh, acc, 0, 0, 0);
      acc = __builtin_amdgcn_mfma_f32_16x16x32_bf16(al, bl, acc, 0, 0, 0);
    }
  }
  // C layout: col = lane&15, row = (lane>>4)*4 + ri
  if (j < E) {
    #pragma unroll
    for (int ri = 0; ri < 4; ++ri)
      gl_s[w * 16 + g * 4 + ri][j] = acc[ri];
  }
  __syncthreads();
  if (t < 64) {
    const int tok = bm * 64 + t;
    float gv[E];
    #pragma unroll
    for (int e2 = 0; e2 < E; ++e2) gv[e2] = gl_s[t][e2] + bg[e2];

    // top-4 gap check (membership boundary = rank2 vs rank3, 0-indexed)
    float s4[4];
    {
      bool used[E] = {};
      #pragma unroll
      for (int k = 0; k < 4; ++k) {
        float best = -1e30f; int bi = 0;
        for (int e2 = 0; e2 < E; ++e2)
          if (!used[e2] && gv[e2] > best) { best = gv[e2]; bi = e2; }
        used[bi] = true; s4[k] = best;
      }
    }
    unsigned long long flags = __ballot(s4[2] - s4[3] < 4e-3f);
    while (flags) {
      const int fl = __ffsll((long long)flags) - 1;
      flags &= flags - 1;
      const int tokf = bm * 64 + fl;
      float ex[E] = {};
      for (int i = 0; i < 16; ++i) {
        const int d = t + 64 * i;
        float xv = x[(size_t)tokf * D + d];
        const float* wr = Wg + (size_t)d * E;
        #pragma unroll
        for (int e2 = 0; e2 < E; ++e2) ex[e2] += xv * wr[e2];
      }
      #pragma unroll
      for (int e2 = 0; e2 < E; ++e2) {
        float s = ex[e2];
        s += __shfl_xor(s, 1); s += __shfl_xor(s, 2); s += __shfl_xor(s, 4);
        s += __shfl_xor(s, 8); s += __shfl_xor(s, 16); s += __shfl_xor(s, 32);
        ex[e2] = s;
      }
      if (t == fl) {
        #pragma unroll
        for (int e2 = 0; e2 < E; ++e2) gv[e2] = ex[e2] + bg[e2];
      }
    }
    // top-3 + softmax + ballot compaction
    int idx[K]; float sc[K];
    bool used[E] = {};
    #pragma unroll
    for (int k = 0; k < K; ++k) {
      float best = -1e30f; int bi = 0;
      for (int e2 = 0; e2 < E; ++e2)
        if (!used[e2] && gv[e2] > best) { best = gv[e2]; bi = e2; }
      used[bi] = true; sc[k] = best; idx[k] = bi;
    }
    float s1 = __expf(sc[1] - sc[0]), s2 = __expf(sc[2] - sc[0]);
    float inv_s = 1.f / (1.f + s1 + s2);
    float tw[K] = {inv_s, s1 * inv_s, s2 * inv_s};
    const unsigned long long below = (1ULL << t) - 1ULL;
    #pragma unroll
    for (int e2 = 0; e2 < E; ++e2) {
      int myk = -1;
      #pragma unroll
      for (int k = 0; k < K; ++k) if (idx[k] == e2) myk = k;
      unsigned long long m = __ballot(myk >= 0);
      if (m) {
        int tot = __popcll(m);
        int leader = __ffsll((long long)m) - 1;
        int base = 0;
        if (t == leader) base = atomicAdd(&cnt[e2], tot);
        base = __shfl(base, leader);
        if (myk >= 0) {
          int pos = base + __popcll(m & below);
          clist[e2 * B + pos] = (tok << 2) | myk;
          wlist[e2 * B + pos] = tw[myk];
        }
      }
    }
  }
}

// ---------------- K5: compacted per-expert GEMM + relu·W2 epilogue ----------
template<int AMODE>
__global__ __launch_bounds__(256) void k_gemm(
    const float* __restrict__ x, const unsigned short* __restrict__ xbf,
    const unsigned short* __restrict__ W1eT,
    const int* __restrict__ cnt, const int* __restrict__ clist,
    const float* __restrict__ wlist,
    const float* __restrict__ b1c, const float* __restrict__ W2,
    const float* __restrict__ b2, float* __restrict__ eo4) {
  __shared__ __align__(16) char ldsA[128 * 128];
  __shared__ __align__(16) char ldsB[128 * 128];
  __shared__ int tokl[128];
  __shared__ float red[128];

  const int t = threadIdx.x;
  const int e = blockIdx.x >> 8;     // grid = E * 256
  const int bm = blockIdx.x & 255;
  const int n = cnt[e];
  if (bm * 128 >= n) return;
  const int cb = e * B;

  if (t < 128) {
    int gr = bm * 128 + t;
    tokl[t] = clist[cb + (gr < n ? gr : 0)] >> 2;
  }
  __syncthreads();

  const int w = t >> 6, lane = t & 63;
  const int g = lane >> 4, j = lane & 15;
  const int swz = ((lane & 7) * 16) ^ ((lane >> 3) << 4);

  const char* srcB[4];
  #pragma unroll
  for (int q = 0; q < 4; ++q)
    srcB[q] = (const char*)W1eT +
              (size_t)(e * HID + w * 32 + q * 8 + (lane >> 3)) * (D * 2) + swz;
  const char* srcA[4];
  if (AMODE == 0) {
    #pragma unroll
    for (int q = 0; q < 4; ++q)
      srcA[q] = (const char*)xbf +
                (size_t)tokl[w * 32 + q * 8 + (lane >> 3)] * 2048 + swz;
  }

  f32x4 acc[2][8] = {};

  for (int kt = 0; kt < NKT; ++kt) {
    if (kt) __syncthreads();
    if (AMODE == 0) {
      #pragma unroll
      for (int q = 0; q < 4; ++q)
        gload_lds16(srcA[q] + kt * 128, ldsA + w * 4096 + q * 1024);
    }
    #pragma unroll
    for (int q = 0; q < 4; ++q)
      gload_lds16(srcB[q] + kt * 128, ldsB + w * 4096 + q * 1024);
    if (AMODE == 1) {
      #pragma unroll
      for (int it = 0; it < 8; ++it) {
        int r = (t >> 4) + it * 16;
        const float4 v =
            *(const float4*)(x + (size_t)tokl[r] * D + kt * 64 + (t & 15) * 4);
        ushort4 h4;
        h4.x = f2bf(v.x); h4.y = f2bf(v.y); h4.z = f2bf(v.z); h4.w = f2bf(v.w);
        *(ushort4*)(ldsA + r * 128 + (((t & 15) * 8) ^ ((r & 7) << 4))) = h4;
      }
    }
    __syncthreads();
    #pragma unroll
    for (int kk = 0; kk < 2; ++kk) {
      const int kb = kk * 64 + g * 16;
      bf16x8 aF[2];
      #pragma unroll
      for (int fm = 0; fm < 2; ++fm) {
        int row = w * 32 + fm * 16 + j;
        aF[fm] = *(const bf16x8*)(ldsA + row * 128 + (kb ^ ((row & 7) << 4)));
      }
      #pragma unroll
      for (int fn = 0; fn < 8; ++fn) {
        int col = fn * 16 + j;
        bf16x8 bF = *(const bf16x8*)(ldsB + col * 128 + (kb ^ ((col & 7) << 4)));
        acc[0][fn] = __builtin_amdgcn_mfma_f32_16x16x32_bf16(aF[0], bF, acc[0][fn], 0, 0, 0);
        acc[1][fn] = __builtin_amdgcn_mfma_f32_16x16x32_bf16(aF[1], bF, acc[1][fn], 0, 0, 0);
      }
    }
  }

  float vb1[8], vw2[8];
  #pragma unroll
  for (int fn = 0; fn < 8; ++fn) {
    int col = fn * 16 + j;
    vb1[fn] = b1c[e * HID + col];
    vw2[fn] = W2[e * HID + col];
  }
  #pragma unroll
  for (int fm = 0; fm < 2; ++fm) {
    #pragma unroll
    for (int r = 0; r < 4; ++r) {
      float s = 0.f;
      #pragma unroll
      for (int fn = 0; fn < 8; ++fn)
        s += fmaxf(acc[fm][fn][r] + vb1[fn], 0.f) * vw2[fn];
      s += __shfl_xor(s, 1); s += __shfl_xor(s, 2);
      s += __shfl_xor(s, 4); s += __shfl_xor(s, 8);
      if (j == 0) red[w * 32 + fm * 16 + g * 4 + r] = s;
    }
  }
  __syncthreads();
  if (t < 128) {
    int gr = bm * 128 + t;
    if (gr < n) {
      int en = clist[cb + gr];
      eo4[(size_t)(en >> 2) * 4 + (en & 3)] = wlist[cb + gr] * (red[t] + b2[e]);
    }
  }
}

// ---------------- K6: sum the 3 weighted slots ----------------
__global__ void k_comb2(const float* __restrict__ eo4, float* __restrict__ out) {
  const int tok = blockIdx.x * 256 + threadIdx.x;
  float4 v = *(const float4*)(eo4 + (size_t)tok * 4);
  out[tok] = v.x + v.y + v.z;
}

extern "C" void kernel_launch(void* const* d_in, const int* in_sizes, int n_in,
                              void* d_out, int out_size, void* d_ws, size_t ws_size,
                              hipStream_t stream) {
  const float* x   = (const float*)d_in[0];
  const float* Wv  = (const float*)d_in[3];
  const float* Wo  = (const float*)d_in[4];
  const float* bo  = (const float*)d_in[5];
  const float* Wsp = (const float*)d_in[6];
  const float* bsp = (const float*)d_in[7];
  const float* Wg  = (const float*)d_in[8];
  const float* bg  = (const float*)d_in[9];
  const float* ml  = (const float*)d_in[10];
  const float* W1  = (const float*)d_in[11];
  const float* b1  = (const float*)d_in[12];
  const float* W2  = (const float*)d_in[13];
  const float* b2  = (const float*)d_in[14];
  float* out = (float*)d_out;

  char* ws = (char*)d_ws;
  int*   inv   = (int*)ws;                          // 24 KB
  float* WoWsp = (float*)(ws + 32768);              // 8 KB
  float* Wfull = (float*)(ws + 49152);              // 64 KB
  float* bfull = (float*)(ws + 114688);             // 128 B
  float* b1c   = (float*)(ws + 118784);             // 3 KB
  int*   cnt   = (int*)(ws + 126976);               // 32 B
  unsigned short* WgS = (unsigned short*)(ws + 131072);  // 64 KB -> 196608
  int*   clist = (int*)(ws + 262144);               // 768 KB -> 1048576
  float* wlist = (float*)(ws + 1048576);            // 768 KB -> 1835008
  float* eo4   = (float*)(ws + 1835008);            // 512 KB -> 2359296
  unsigned short* W1eT = (unsigned short*)(ws + 2359296);  // 1.5 MB -> 3932160
  unsigned short* xbf  = (unsigned short*)(ws + 3932160);  // 64 MB (optional)
  const bool use_xbf = ws_size >= (size_t)3932160 + (size_t)B * D * 2;

  k_sel<<<E, D, 0, stream>>>(ml, inv, cnt);
  k_wowsp<<<129, 256, 0, stream>>>(Wo, Wsp, bo, bsp, Wg, WoWsp, bfull, WgS);
  k_wfull2<<<64, 256, 0, stream>>>(Wv, WoWsp, Wfull);
  k_w1c<<<E * HID, 256, 0, stream>>>(W1, b1, inv, Wfull, bfull, W1eT, b1c);
  if (use_xbf)
    k_xgate<true><<<B / 64, 256, 0, stream>>>(x, WgS, Wg, bg, xbf, cnt, clist, wlist);
  else
    k_xgate<false><<<B / 64, 256, 0, stream>>>(x, WgS, Wg, bg, xbf, cnt, clist, wlist);
  if (use_xbf)
    k_gemm<0><<<E * 256, 256, 0, stream>>>(x, xbf, W1eT, cnt, clist, wlist, b1c, W2, b2, eo4);
  else
    k_gemm<1><<<E * 256, 256, 0, stream>>>(x, xbf, W1eT, cnt, clist, wlist, b1c, W2, b2, eo4);
  k_comb2<<<B / 256, 256, 0, stream>>>(eo4, out);
}